// Round 1
// 307.860 us; speedup vs baseline: 1.0162x; 1.0162x over previous
//
#include <hip/hip_runtime.h>
#include <cstdint>

// GCN via radix partition (bucket = node>>9), packed u32 edge records.
// part1c: LDS-staged local counting sort -> ordered run writes.
// Z fp8-e4m3 (12.8 MB). pooled = P^T H via MFMA (P blocked bf16), fold, tiny out.
// layer1 v2: quarter-wave dwordx2 gathers (4 edges/wave in lockstep, 16-edge
//            pipelined main loop with srcS index prefetch).

#define DD 128
#define PB 512    // partition pass-1 blocks
#define GB 384    // poolgemm split-K blocks (part aliased onto pairD+pairS)
#define KC 32     // poolgemm K-chunk
#define CHK 3200  // max edges per part1c block

typedef __attribute__((ext_vector_type(8))) short bf16x8;
typedef __attribute__((ext_vector_type(4))) float f32x4;
typedef __attribute__((ext_vector_type(2))) float f32x2;

__device__ __forceinline__ unsigned short f2bf(float f) {
  union { float f; unsigned u; } v; v.f = f;
  unsigned r = (v.u + 0x7fff + ((v.u >> 16) & 1)) >> 16;   // round-nearest-even
  return (unsigned short)r;
}
__device__ __forceinline__ float bfhi(unsigned u) {
  union { unsigned u; float f; } v; v.u = u & 0xffff0000u; return v.f;
}
__device__ __forceinline__ float bflo(unsigned u) {
  union { unsigned u; float f; } v; v.u = u << 16; return v.f;
}
__device__ __forceinline__ unsigned char f2fp8(float f) {
  return (unsigned char)(__builtin_amdgcn_cvt_pk_fp8_f32(f, f, 0, false) & 0xff);
}

// ---- pass 1a: per-block 256-bin LDS histograms of dst>>9 and src>>9 + gcnt ----
__global__ __launch_bounds__(256) void k_part1a(const int* __restrict__ src, const int* __restrict__ dst,
                                                const int* __restrict__ gid,
                                                unsigned* __restrict__ histD, unsigned* __restrict__ histS,
                                                int* __restrict__ gcnt, int E, int N, int G) {
  __shared__ unsigned hD[256], hS[256];
  __shared__ int h64[64];
  hD[threadIdx.x] = 0; hS[threadIdx.x] = 0;
  if (threadIdx.x < 64) h64[threadIdx.x] = 0;
  __syncthreads();
  int chunk = (E + gridDim.x - 1) / gridDim.x;
  int e0 = blockIdx.x * chunk, e1 = min(E, e0 + chunk);
  for (int e = e0 + threadIdx.x; e < e1; e += 256) {
    atomicAdd(&hD[(unsigned)dst[e] >> 9], 1u);
    atomicAdd(&hS[(unsigned)src[e] >> 9], 1u);
  }
  int stride = gridDim.x * 256;
  for (int i = blockIdx.x * 256 + threadIdx.x; i < N; i += stride)
    atomicAdd(&h64[gid[i]], 1);
  __syncthreads();
  histD[blockIdx.x * 256 + threadIdx.x] = hD[threadIdx.x];
  histS[blockIdx.x * 256 + threadIdx.x] = hS[threadIdx.x];
  if (threadIdx.x < (unsigned)G) {
    int v = h64[threadIdx.x];
    if (v) atomicAdd(&gcnt[threadIdx.x], v);
  }
}

// ---- pscanA: per (table,bucket) — scan the PB per-block counts ----
__global__ __launch_bounds__(256) void k_pscanA(unsigned* __restrict__ histD, unsigned* __restrict__ histS,
                                                unsigned* __restrict__ tot) {
  __shared__ unsigned excl[PB], psc[256];
  int table = blockIdx.x >> 8, b = blockIdx.x & 255;
  unsigned* hist = table ? histS : histD;
  int t = threadIdx.x;
  unsigned s0 = hist[(2 * t) * 256 + b];
  unsigned s1 = hist[(2 * t + 1) * 256 + b];
  unsigned pr = s0 + s1;
  psc[t] = pr;
  __syncthreads();
  for (int off = 1; off < 256; off <<= 1) {
    unsigned x = (t >= off) ? psc[t - off] : 0;
    __syncthreads();
    psc[t] += x;
    __syncthreads();
  }
  unsigned pex = psc[t] - pr;
  excl[2 * t] = pex;
  excl[2 * t + 1] = pex + s0;
  __syncthreads();
  hist[(2 * t) * 256 + b] = excl[2 * t];
  hist[(2 * t + 1) * 256 + b] = excl[2 * t + 1];
  if (t == 255) tot[table * 256 + b] = psc[255];
}

// ---- pscanB: one block — scan bucket totals for both tables ----
__global__ __launch_bounds__(256) void k_pscanB(const unsigned* __restrict__ tot,
                                                int* __restrict__ bsD, int* __restrict__ bsS) {
  __shared__ unsigned s[256];
  int t = threadIdx.x;
#pragma unroll
  for (int table = 0; table < 2; ++table) {
    int* bs = table ? bsS : bsD;
    unsigned v = tot[table * 256 + t];
    s[t] = v;
    __syncthreads();
    for (int off = 1; off < 256; off <<= 1) {
      unsigned x = (t >= off) ? s[t - off] : 0;
      __syncthreads();
      s[t] += x;
      __syncthreads();
    }
    bs[t] = (int)(s[t] - v);
    if (t == 255) bs[256] = (int)s[255];
    __syncthreads();
  }
}

// ---- pscanC: add bucket base into per-(block,bucket) cursors ----
__global__ __launch_bounds__(256) void k_pscanC(unsigned* __restrict__ histD, unsigned* __restrict__ histS,
                                                const int* __restrict__ bsD, const int* __restrict__ bsS) {
  int table = blockIdx.x >> 9, i = blockIdx.x & (PB - 1);
  unsigned* hist = table ? histS : histD;
  const int* bs = table ? bsS : bsD;
  hist[i * 256 + threadIdx.x] += (unsigned)bs[threadIdx.x];
}

// ---- pass 1c: LDS-staged local counting sort, then ORDERED run write-out ----
// pairD: (dst&511)<<17 | src ; pairS: (src&511)<<17 | dst   (N < 2^17)
__global__ __launch_bounds__(256) void k_part1c(const int* __restrict__ src, const int* __restrict__ dst,
                                                const unsigned* __restrict__ histD, const unsigned* __restrict__ histS,
                                                unsigned* __restrict__ pairD, unsigned* __restrict__ pairS, int E) {
  __shared__ unsigned pk[CHK];
  __shared__ unsigned char bk[CHK];
  __shared__ unsigned hist[256], cur[256], gbase[256], psc[256];
  int chunk = (E + gridDim.x - 1) / gridDim.x;
  int e0 = blockIdx.x * chunk, e1 = min(E, e0 + chunk);
  int n = e1 - e0;
  int t = threadIdx.x;
#pragma unroll
  for (int table = 0; table < 2; ++table) {
    const unsigned* gcur = (table ? histS : histD) + blockIdx.x * 256;
    unsigned* out = table ? pairS : pairD;
    hist[t] = 0;
    __syncthreads();
    for (int i = t; i < n; i += 256) {
      unsigned key = (unsigned)(table ? src[e0 + i] : dst[e0 + i]);
      atomicAdd(&hist[key >> 9], 1u);
    }
    __syncthreads();
    unsigned v = hist[t];
    psc[t] = v;
    __syncthreads();
    for (int off = 1; off < 256; off <<= 1) {
      unsigned x = (t >= off) ? psc[t - off] : 0;
      __syncthreads();
      psc[t] += x;
      __syncthreads();
    }
    unsigned excl = psc[t] - v;
    cur[t] = excl;
    gbase[t] = gcur[t] - excl;
    __syncthreads();
    for (int i = t; i < n; i += 256) {
      unsigned sv = (unsigned)src[e0 + i], dv = (unsigned)dst[e0 + i];
      unsigned key = table ? sv : dv;
      unsigned val = table ? (((sv & 511u) << 17) | dv) : (((dv & 511u) << 17) | sv);
      unsigned b = key >> 9;
      unsigned p = atomicAdd(&cur[b], 1u);
      pk[p] = val;
      bk[p] = (unsigned char)b;
    }
    __syncthreads();
    for (int i = t; i < n; i += 256)
      out[gbase[bk[i]] + i] = pk[i];
    __syncthreads();
  }
}

// ---- pass 2d: per dst-bucket — hist, scan, write offs/degI, place srcS ----
__global__ __launch_bounds__(256) void k_part2d(const unsigned* __restrict__ pairD, const int* __restrict__ bsD,
                                                int* __restrict__ offs, int* __restrict__ degI,
                                                int* __restrict__ srcS, int N) {
  __shared__ unsigned hist[512], excl[512], psc[256];
  int k = blockIdx.x, base = k << 9;
  int b0 = bsD[k], b1 = bsD[k + 1];
  hist[threadIdx.x] = 0; hist[threadIdx.x + 256] = 0;
  __syncthreads();
  for (int i = b0 + threadIdx.x; i < b1; i += 256)
    atomicAdd(&hist[pairD[i] >> 17], 1u);
  __syncthreads();
  unsigned s0 = hist[2 * threadIdx.x], s1 = hist[2 * threadIdx.x + 1];
  unsigned pr = s0 + s1;
  psc[threadIdx.x] = pr;
  __syncthreads();
  for (int off = 1; off < 256; off <<= 1) {
    unsigned x = (threadIdx.x >= off) ? psc[threadIdx.x - off] : 0;
    __syncthreads();
    psc[threadIdx.x] += x;
    __syncthreads();
  }
  unsigned pex = psc[threadIdx.x] - pr;
  excl[2 * threadIdx.x] = pex;
  excl[2 * threadIdx.x + 1] = pex + s0;
  __syncthreads();
  for (int j = threadIdx.x; j < 512; j += 256) {
    int node = base + j;
    if (node <= N) offs[node] = b0 + (int)excl[j];
    if (node < N) degI[node] = (int)hist[j];
  }
  __syncthreads();
  for (int i = b0 + threadIdx.x; i < b1; i += 256) {
    unsigned pkv = pairD[i];
    unsigned pos = atomicAdd(&excl[pkv >> 17], 1u);
    srcS[b0 + (int)pos] = (int)(pkv & 0x1FFFFu);
  }
}

// ---- norms for dst side + packed (poolw, gid) ----
__global__ __launch_bounds__(256) void k_norm(const int* __restrict__ degI, const int* __restrict__ gcnt,
                                              const int* __restrict__ gid,
                                              float* __restrict__ ndst, uint2* __restrict__ pwg, int N) {
  int i = blockIdx.x * blockDim.x + threadIdx.x;
  if (i >= N) return;
  float gi = (float)degI[i]; gi = gi > 0.f ? gi : 1.f;
  float nd = rsqrtf(gi);
  ndst[i] = nd;
  float c = (float)gcnt[gid[i]]; c = c > 1.f ? c : 1.f;
  float w = nd / c;
  union { float f; unsigned u; } v; v.f = w;
  pwg[i] = make_uint2(v.u, (unsigned)gid[i]);
}

// ---- k_pw (fused part2s): per src-bucket — out-degree hist -> nsrc,
//      and 128 KB LDS P-tile -> blocked bf16 P_blk[(k>>3)][g][k&7] ----
__global__ __launch_bounds__(1024, 1) void k_pw(const unsigned* __restrict__ pairS, const int* __restrict__ bsS,
                                                const uint2* __restrict__ pwg,
                                                unsigned short* __restrict__ P16,
                                                float* __restrict__ nsrc, int N) {
  __shared__ float tile[512 * 64];   // 128 KB
  __shared__ unsigned hist[512];     // 2 KB
  int k = blockIdx.x, base = k << 9;
  int b0 = bsS[k], b1 = bsS[k + 1];
  for (int i = threadIdx.x; i < 512 * 64; i += 1024) tile[i] = 0.f;
  if (threadIdx.x < 512) hist[threadIdx.x] = 0;
  __syncthreads();
  for (int i = b0 + threadIdx.x; i < b1; i += 1024) {
    unsigned pkv = pairS[i];
    unsigned dv = pkv & 0x1FFFFu;
    unsigned sloc = pkv >> 17;
    atomicAdd(&hist[sloc], 1u);
    uint2 u = pwg[dv];
    union { unsigned u; float f; } w; w.u = u.x;
    atomicAdd(&tile[sloc * 64 + u.y], w.f);
  }
  __syncthreads();
  if (threadIdx.x < 512) {
    int node = base + threadIdx.x;
    if (node < N) {
      float g = (float)hist[threadIdx.x]; g = g > 0.f ? g : 1.f;
      nsrc[node] = rsqrtf(g);
    }
  }
  // blocked bf16 write: rows >= N are zero (tile untouched) -> poolgemm needs no K guard
  for (int grp = threadIdx.x; grp < 4096; grp += 1024) {
    int qb = grp >> 6, g = grp & 63;
    unsigned w0 = (unsigned)f2bf(tile[(qb * 8 + 0) * 64 + g]) | ((unsigned)f2bf(tile[(qb * 8 + 1) * 64 + g]) << 16);
    unsigned w1 = (unsigned)f2bf(tile[(qb * 8 + 2) * 64 + g]) | ((unsigned)f2bf(tile[(qb * 8 + 3) * 64 + g]) << 16);
    unsigned w2 = (unsigned)f2bf(tile[(qb * 8 + 4) * 64 + g]) | ((unsigned)f2bf(tile[(qb * 8 + 5) * 64 + g]) << 16);
    unsigned w3 = (unsigned)f2bf(tile[(qb * 8 + 6) * 64 + g]) | ((unsigned)f2bf(tile[(qb * 8 + 7) * 64 + g]) << 16);
    uint4 o = make_uint4(w0, w1, w2, w3);
    *(uint4*)(P16 + ((size_t)(base >> 3) + qb) * 512 + g * 8) = o;
  }
}

// ---- wprep: Wt[n][k] = bf16(W1[k][n]) ----
__global__ __launch_bounds__(128) void k_wprep(const float* __restrict__ W, unsigned short* __restrict__ Wt) {
  int n = blockIdx.x, k = threadIdx.x;
  Wt[n * 128 + k] = f2bf(W[k * 128 + n]);
}

// ---- GEMM1 (MFMA): Z8 = fp8( (X @ W1) * nsrc[row] ), LDS-free ----
__global__ __launch_bounds__(256) void k_gemm1(const float* __restrict__ X, const unsigned short* __restrict__ Wt,
                                               const float* __restrict__ nsrc,
                                               unsigned char* __restrict__ Z8, int N) {
  int wave = threadIdx.x >> 6, lane = threadIdx.x & 63;
  int quad = lane >> 4, l16 = lane & 15;
  int row0 = blockIdx.x * 64 + wave * 16;
  int arow = row0 + l16; if (arow >= N) arow = N - 1;
  const float* xr = X + (size_t)arow * 128 + quad * 8;
  f32x4 acc[8];
#pragma unroll
  for (int i = 0; i < 8; ++i) acc[i] = (f32x4){0.f, 0.f, 0.f, 0.f};
#pragma unroll
  for (int kb = 0; kb < 128; kb += 32) {
    float4 x0 = *(const float4*)(xr + kb);
    float4 x1 = *(const float4*)(xr + kb + 4);
    bf16x8 a;
    a[0] = (short)f2bf(x0.x); a[1] = (short)f2bf(x0.y);
    a[2] = (short)f2bf(x0.z); a[3] = (short)f2bf(x0.w);
    a[4] = (short)f2bf(x1.x); a[5] = (short)f2bf(x1.y);
    a[6] = (short)f2bf(x1.z); a[7] = (short)f2bf(x1.w);
#pragma unroll
    for (int nt = 0; nt < 8; ++nt) {
      bf16x8 b = *(const bf16x8*)(Wt + (size_t)(nt * 16 + l16) * 128 + kb + quad * 8);
      acc[nt] = __builtin_amdgcn_mfma_f32_16x16x32_bf16(a, b, acc[nt], 0, 0, 0);
    }
  }
  int rbase = row0 + quad * 4;
#pragma unroll
  for (int r = 0; r < 4; ++r) {
    int row = rbase + r;
    if (row < N) {
      float s = nsrc[row];
#pragma unroll
      for (int nt = 0; nt < 8; ++nt)
        Z8[(size_t)row * 128 + nt * 16 + l16] = f2fp8(acc[nt][r] * s);
    }
  }
}

// ---- layer1 v2: per-dst gather-reduce (fp8 rows, quarter-wave dwordx2) ----
// 4 edges of the SAME dst in lockstep (one per 16-lane quarter, 8 B/lane).
// Main loop: 16 edges/iter, next iteration's srcS indices prefetched before
// the gathers are consumed (breaks the srcS->gather dependent chain).
#define ACC8(u) do {                                              \
    f32x2 p0 = __builtin_amdgcn_cvt_pk_f32_fp8((u).x, false);     \
    f32x2 p1 = __builtin_amdgcn_cvt_pk_f32_fp8((u).x, true);      \
    f32x2 p2 = __builtin_amdgcn_cvt_pk_f32_fp8((u).y, false);     \
    f32x2 p3 = __builtin_amdgcn_cvt_pk_f32_fp8((u).y, true);      \
    a0 += p0[0]; a1 += p0[1]; a2 += p1[0]; a3 += p1[1];           \
    a4 += p2[0]; a5 += p2[1]; a6 += p3[0]; a7 += p3[1];           \
  } while (0)

__global__ __launch_bounds__(256) void k_layer1(const unsigned char* __restrict__ Z8,
                                                const int* __restrict__ offs, const int* __restrict__ srcS,
                                                const float* __restrict__ b1,
                                                const float* __restrict__ nsrc, const float* __restrict__ ndst,
                                                unsigned short* __restrict__ Hb, int N) {
  int lane = threadIdx.x & 63;
  int q = lane >> 4, l16 = lane & 15;
  int d = blockIdx.x * 4 + (threadIdx.x >> 6);
  if (d >= N) return;
  int start = offs[d], end = offs[d + 1];
  // hoist epilogue operands early (hide their latency under the gather loop)
  const float* bp = b1 + l16 * 8;
  float4 bv0 = *(const float4*)bp;
  float4 bv1 = *(const float4*)(bp + 4);
  float nd = ndst[d], ns = nsrc[d];
  float a0 = 0.f, a1 = 0.f, a2 = 0.f, a3 = 0.f;
  float a4 = 0.f, a5 = 0.f, a6 = 0.f, a7 = 0.f;
  const int boff = l16 * 8;
  int e = start;
  if (e + 16 <= end) {
    int s0 = srcS[e + q], s1 = srcS[e + 4 + q];
    int s2 = srcS[e + 8 + q], s3 = srcS[e + 12 + q];
    for (;;) {
      uint2 u0 = *(const uint2*)(Z8 + ((size_t)s0 << 7) + boff);
      uint2 u1 = *(const uint2*)(Z8 + ((size_t)s1 << 7) + boff);
      uint2 u2 = *(const uint2*)(Z8 + ((size_t)s2 << 7) + boff);
      uint2 u3 = *(const uint2*)(Z8 + ((size_t)s3 << 7) + boff);
      e += 16;
      bool more = (e + 16 <= end);     // wave-uniform: d is per-wave
      if (more) {
        s0 = srcS[e + q]; s1 = srcS[e + 4 + q];
        s2 = srcS[e + 8 + q]; s3 = srcS[e + 12 + q];
      }
      ACC8(u0); ACC8(u1); ACC8(u2); ACC8(u3);
      if (!more) break;
    }
  }
  for (; e + 4 <= end; e += 4) {
    int s = srcS[e + q];
    uint2 u = *(const uint2*)(Z8 + ((size_t)s << 7) + boff);
    ACC8(u);
  }
  if (e < end) {                        // 1..3 ragged edges, predicated
    int idx = e + q;
    int s = srcS[idx < end ? idx : end - 1];
    uint2 u = *(const uint2*)(Z8 + ((size_t)s << 7) + boff);
    if (idx < end) ACC8(u);
  }
  // reduce across the 4 quarters
  a0 += __shfl_xor(a0, 16, 64); a0 += __shfl_xor(a0, 32, 64);
  a1 += __shfl_xor(a1, 16, 64); a1 += __shfl_xor(a1, 32, 64);
  a2 += __shfl_xor(a2, 16, 64); a2 += __shfl_xor(a2, 32, 64);
  a3 += __shfl_xor(a3, 16, 64); a3 += __shfl_xor(a3, 32, 64);
  a4 += __shfl_xor(a4, 16, 64); a4 += __shfl_xor(a4, 32, 64);
  a5 += __shfl_xor(a5, 16, 64); a5 += __shfl_xor(a5, 32, 64);
  a6 += __shfl_xor(a6, 16, 64); a6 += __shfl_xor(a6, 32, 64);
  a7 += __shfl_xor(a7, 16, 64); a7 += __shfl_xor(a7, 32, 64);
  if (q == 0) {
    float h0 = fmaxf(fmaf(nd, a0, bv0.x), 0.f) * ns;
    float h1 = fmaxf(fmaf(nd, a1, bv0.y), 0.f) * ns;
    float h2 = fmaxf(fmaf(nd, a2, bv0.z), 0.f) * ns;
    float h3 = fmaxf(fmaf(nd, a3, bv0.w), 0.f) * ns;
    float h4 = fmaxf(fmaf(nd, a4, bv1.x), 0.f) * ns;
    float h5 = fmaxf(fmaf(nd, a5, bv1.y), 0.f) * ns;
    float h6 = fmaxf(fmaf(nd, a6, bv1.z), 0.f) * ns;
    float h7 = fmaxf(fmaf(nd, a7, bv1.w), 0.f) * ns;
    unsigned w0 = (unsigned)f2bf(h0) | ((unsigned)f2bf(h1) << 16);
    unsigned w1 = (unsigned)f2bf(h2) | ((unsigned)f2bf(h3) << 16);
    unsigned w2 = (unsigned)f2bf(h4) | ((unsigned)f2bf(h5) << 16);
    unsigned w3 = (unsigned)f2bf(h6) | ((unsigned)f2bf(h7) << 16);
    *(uint4*)(Hb + (size_t)d * 128 + boff) = make_uint4(w0, w1, w2, w3);
  }
}

// ---- k_poolgemm (MFMA): part[b] = P_blk^T · H  (split-K, bf16 inputs, f32 acc) ----
// wave w owns g-tile w; A-frag = one 16B load from P_blk; B-frag from swizzled LDS H.
__global__ __launch_bounds__(256) void k_poolgemm(const unsigned short* __restrict__ P16,
                                                  const unsigned short* __restrict__ Hb,
                                                  float* __restrict__ part, int N, int Kpad, int chunk) {
  __shared__ unsigned short Hl[KC * 128];   // 8 KB, 16-short groups XOR-swizzled by (row>>3)
  int t = threadIdx.x;
  int r0 = blockIdx.x * chunk;
  int r1 = min(Kpad, r0 + chunk);
  int wv = t >> 6, lane = t & 63, quad = lane >> 4, l16 = lane & 15;
  f32x4 acc[8];
#pragma unroll
  for (int i = 0; i < 8; ++i) acc[i] = (f32x4){0.f, 0.f, 0.f, 0.f};
  for (int rb = r0; rb < r1; rb += KC) {
    int r = t >> 3, c = (t & 7) * 16;
    int cs = c ^ ((r >> 3) * 16);        // swizzle 16-short group by row-octet
    int row = rb + r;
    if (row < N) {
      const uint4* srcp = (const uint4*)(Hb + (size_t)row * 128 + c);
      *(uint4*)(Hl + r * 128 + cs) = srcp[0];
      *(uint4*)(Hl + r * 128 + cs + 8) = srcp[1];
    } else {
      uint4 z = make_uint4(0, 0, 0, 0);
      *(uint4*)(Hl + r * 128 + cs) = z;
      *(uint4*)(Hl + r * 128 + cs + 8) = z;
    }
    __syncthreads();
    bf16x8 a = *(const bf16x8*)(P16 + ((size_t)(rb >> 3) + quad) * 512 + (wv * 16 + l16) * 8);
#pragma unroll
    for (int ft = 0; ft < 8; ++ft) {
      bf16x8 b;
#pragma unroll
      for (int j = 0; j < 8; ++j) {
        int rr = quad * 8 + j;
        b[j] = (short)Hl[rr * 128 + ((ft ^ (rr >> 3)) * 16) + l16];
      }
      acc[ft] = __builtin_amdgcn_mfma_f32_16x16x32_bf16(a, b, acc[ft], 0, 0, 0);
    }
    __syncthreads();
  }
  float* bp = part + (size_t)blockIdx.x * 64 * DD;
#pragma unroll
  for (int ft = 0; ft < 8; ++ft)
#pragma unroll
    for (int rg = 0; rg < 4; ++rg)
      bp[(wv * 16 + quad * 4 + rg) * DD + ft * 16 + l16] = acc[ft][rg];
}

// ---- fold split-K partials into pooled (zero-init) ----
__global__ __launch_bounds__(256) void k_fold(const float* __restrict__ part, float* __restrict__ pooled) {
  int tid = blockIdx.x * 256 + threadIdx.x;   // grid 256 -> 65536 threads, 8 groups
  int o = tid & 8191, grp = tid >> 13;
  float s = 0.f;
  for (int k = grp; k < GB; k += 8) s += part[(size_t)k * 8192 + o];
  unsafeAtomicAdd(&pooled[o], s);
}

// ---- out = pooled @ W2 + b2 ----
__global__ __launch_bounds__(128) void k_out(const float* __restrict__ pooled, const float* __restrict__ W2,
                                             const float* __restrict__ b2, float* __restrict__ out) {
  __shared__ float p[DD];
  int g = blockIdx.x, d = threadIdx.x;
  p[d] = pooled[g * DD + d];
  __syncthreads();
  float a = b2[d];
#pragma unroll 4
  for (int k = 0; k < DD; ++k) a = fmaf(p[k], W2[k * DD + d], a);
  out[g * DD + d] = a;
}

extern "C" void kernel_launch(void* const* d_in, const int* in_sizes, int n_in,
                              void* d_out, int out_size, void* d_ws, size_t ws_size,
                              hipStream_t stream) {
  const float* X  = (const float*)d_in[0];
  const float* W1 = (const float*)d_in[1];
  const float* b1 = (const float*)d_in[2];
  const float* W2 = (const float*)d_in[3];
  const float* b2 = (const float*)d_in[4];
  const int* src  = (const int*)d_in[5];
  const int* dst  = (const int*)d_in[6];
  const int* gid  = (const int*)d_in[7];
  int E = in_sizes[5];
  int N = in_sizes[7];
  int G = out_size / DD;   // 64
  int nb = (N >> 9) + 1;   // node buckets
  int Kpad = nb << 9;
  int chunk = ((Kpad + GB * KC - 1) / (GB * KC)) * KC;

  char* w = (char*)d_ws;
  size_t o = 0;
  auto carve = [&](size_t bytes) { char* p = w + o; o += (bytes + 255) & ~(size_t)255; return p; };
  // zero-init region
  int*   gcnt   = (int*)  carve((size_t)G * 4);
  float* pooled = (float*)carve((size_t)G * DD * 4);
  size_t zeroBytes = o;
  // rest (fully written before read)
  unsigned* histD = (unsigned*)carve((size_t)PB * 256 * 4);
  unsigned* histS = (unsigned*)carve((size_t)PB * 256 * 4);
  unsigned* tot   = (unsigned*)carve(512 * 4);
  int*   bsD    = (int*)  carve(257 * 4);
  int*   bsS    = (int*)  carve(257 * 4);
  unsigned* pairD = (unsigned*)carve((size_t)E * 4);  // } pairD+pairS (12.8 MB) aliased as part
  unsigned* pairS = (unsigned*)carve((size_t)E * 4);  // }   (GB*32KB = 12.58 MB fits)
  int*   srcS   = (int*)  carve((size_t)E * 4);
  int*   offs   = (int*)  carve((size_t)(N + 1) * 4);
  int*   degI   = (int*)  carve((size_t)N * 4);
  float* nsrc   = (float*)carve((size_t)N * 4);
  float* ndst   = (float*)carve((size_t)N * 4);
  uint2* pwg    = (uint2*)carve((size_t)N * 8);
  unsigned short* Wt = (unsigned short*)carve(128 * 128 * 2);
  unsigned char*  Z8 = (unsigned char*)carve((size_t)N * DD);       // fp8
  unsigned short* Hb = (unsigned short*)carve((size_t)N * DD * 2);
  unsigned short* P16 = (unsigned short*)carve((size_t)Kpad * 64 * 2);  // blocked bf16
  float* part   = (float*)pairD;   // pairD dead after part2d, pairS dead after k_pw

  hipMemsetAsync(d_ws, 0, zeroBytes, stream);

  k_part1a<<<PB, 256, 0, stream>>>(src, dst, gid, histD, histS, gcnt, E, N, G);
  k_pscanA<<<512, 256, 0, stream>>>(histD, histS, tot);
  k_pscanB<<<1, 256, 0, stream>>>(tot, bsD, bsS);
  k_pscanC<<<2 * PB, 256, 0, stream>>>(histD, histS, bsD, bsS);
  k_part1c<<<PB, 256, 0, stream>>>(src, dst, histD, histS, pairD, pairS, E);
  k_part2d<<<nb, 256, 0, stream>>>(pairD, bsD, offs, degI, srcS, N);
  k_norm<<<(N + 255) / 256, 256, 0, stream>>>(degI, gcnt, gid, ndst, pwg, N);
  k_pw<<<nb, 1024, 0, stream>>>(pairS, bsS, pwg, P16, nsrc, N);
  k_wprep<<<128, 128, 0, stream>>>(W1, Wt);
  k_gemm1<<<(N + 63) / 64, 256, 0, stream>>>(X, Wt, nsrc, Z8, N);
  k_layer1<<<(N + 3) / 4, 256, 0, stream>>>(Z8, offs, srcS, b1, nsrc, ndst, Hb, N);
  k_poolgemm<<<GB, 256, 0, stream>>>(P16, Hb, part, N, Kpad, chunk);
  k_fold<<<256, 256, 0, stream>>>(part, pooled);
  k_out<<<G, DD, 0, stream>>>(pooled, W2, b2, (float*)d_out);
}

// Round 2
// 298.675 us; speedup vs baseline: 1.0475x; 1.0308x over previous
//
#include <hip/hip_runtime.h>
#include <cstdint>

// GCN via radix partition (bucket = node>>9), packed u32 edge records.
// part1c: LDS-staged local counting sort -> ordered run writes.
// Z fp8-e4m3 (12.8 MB). pooled = P^T H via MFMA (P blocked bf16), fold, tiny out.
// layer1 v3: quarter-wave owns a dst (4 dsts/wave, no cross-lane reduce),
//            packed f32x2 accumulate (v_pk_add_f32), 2-edge pipelined gather.

#define DD 128
#define PB 512    // partition pass-1 blocks
#define GB 384    // poolgemm split-K blocks (part aliased onto pairD+pairS)
#define KC 32     // poolgemm K-chunk
#define CHK 3200  // max edges per part1c block

typedef __attribute__((ext_vector_type(8))) short bf16x8;
typedef __attribute__((ext_vector_type(4))) float f32x4;
typedef __attribute__((ext_vector_type(2))) float f32x2;

__device__ __forceinline__ unsigned short f2bf(float f) {
  union { float f; unsigned u; } v; v.f = f;
  unsigned r = (v.u + 0x7fff + ((v.u >> 16) & 1)) >> 16;   // round-nearest-even
  return (unsigned short)r;
}
__device__ __forceinline__ float bfhi(unsigned u) {
  union { unsigned u; float f; } v; v.u = u & 0xffff0000u; return v.f;
}
__device__ __forceinline__ float bflo(unsigned u) {
  union { unsigned u; float f; } v; v.u = u << 16; return v.f;
}
__device__ __forceinline__ unsigned char f2fp8(float f) {
  return (unsigned char)(__builtin_amdgcn_cvt_pk_fp8_f32(f, f, 0, false) & 0xff);
}

// ---- pass 1a: per-block 256-bin LDS histograms of dst>>9 and src>>9 + gcnt ----
__global__ __launch_bounds__(256) void k_part1a(const int* __restrict__ src, const int* __restrict__ dst,
                                                const int* __restrict__ gid,
                                                unsigned* __restrict__ histD, unsigned* __restrict__ histS,
                                                int* __restrict__ gcnt, int E, int N, int G) {
  __shared__ unsigned hD[256], hS[256];
  __shared__ int h64[64];
  hD[threadIdx.x] = 0; hS[threadIdx.x] = 0;
  if (threadIdx.x < 64) h64[threadIdx.x] = 0;
  __syncthreads();
  int chunk = (E + gridDim.x - 1) / gridDim.x;
  int e0 = blockIdx.x * chunk, e1 = min(E, e0 + chunk);
  for (int e = e0 + threadIdx.x; e < e1; e += 256) {
    atomicAdd(&hD[(unsigned)dst[e] >> 9], 1u);
    atomicAdd(&hS[(unsigned)src[e] >> 9], 1u);
  }
  int stride = gridDim.x * 256;
  for (int i = blockIdx.x * 256 + threadIdx.x; i < N; i += stride)
    atomicAdd(&h64[gid[i]], 1);
  __syncthreads();
  histD[blockIdx.x * 256 + threadIdx.x] = hD[threadIdx.x];
  histS[blockIdx.x * 256 + threadIdx.x] = hS[threadIdx.x];
  if (threadIdx.x < (unsigned)G) {
    int v = h64[threadIdx.x];
    if (v) atomicAdd(&gcnt[threadIdx.x], v);
  }
}

// ---- pscanA: per (table,bucket) — scan the PB per-block counts ----
__global__ __launch_bounds__(256) void k_pscanA(unsigned* __restrict__ histD, unsigned* __restrict__ histS,
                                                unsigned* __restrict__ tot) {
  __shared__ unsigned excl[PB], psc[256];
  int table = blockIdx.x >> 8, b = blockIdx.x & 255;
  unsigned* hist = table ? histS : histD;
  int t = threadIdx.x;
  unsigned s0 = hist[(2 * t) * 256 + b];
  unsigned s1 = hist[(2 * t + 1) * 256 + b];
  unsigned pr = s0 + s1;
  psc[t] = pr;
  __syncthreads();
  for (int off = 1; off < 256; off <<= 1) {
    unsigned x = (t >= off) ? psc[t - off] : 0;
    __syncthreads();
    psc[t] += x;
    __syncthreads();
  }
  unsigned pex = psc[t] - pr;
  excl[2 * t] = pex;
  excl[2 * t + 1] = pex + s0;
  __syncthreads();
  hist[(2 * t) * 256 + b] = excl[2 * t];
  hist[(2 * t + 1) * 256 + b] = excl[2 * t + 1];
  if (t == 255) tot[table * 256 + b] = psc[255];
}

// ---- pscanB: one block — scan bucket totals for both tables ----
__global__ __launch_bounds__(256) void k_pscanB(const unsigned* __restrict__ tot,
                                                int* __restrict__ bsD, int* __restrict__ bsS) {
  __shared__ unsigned s[256];
  int t = threadIdx.x;
#pragma unroll
  for (int table = 0; table < 2; ++table) {
    int* bs = table ? bsS : bsD;
    unsigned v = tot[table * 256 + t];
    s[t] = v;
    __syncthreads();
    for (int off = 1; off < 256; off <<= 1) {
      unsigned x = (t >= off) ? s[t - off] : 0;
      __syncthreads();
      s[t] += x;
      __syncthreads();
    }
    bs[t] = (int)(s[t] - v);
    if (t == 255) bs[256] = (int)s[255];
    __syncthreads();
  }
}

// ---- pscanC: add bucket base into per-(block,bucket) cursors ----
__global__ __launch_bounds__(256) void k_pscanC(unsigned* __restrict__ histD, unsigned* __restrict__ histS,
                                                const int* __restrict__ bsD, const int* __restrict__ bsS) {
  int table = blockIdx.x >> 9, i = blockIdx.x & (PB - 1);
  unsigned* hist = table ? histS : histD;
  const int* bs = table ? bsS : bsD;
  hist[i * 256 + threadIdx.x] += (unsigned)bs[threadIdx.x];
}

// ---- pass 1c: LDS-staged local counting sort, then ORDERED run write-out ----
// pairD: (dst&511)<<17 | src ; pairS: (src&511)<<17 | dst   (N < 2^17)
__global__ __launch_bounds__(256) void k_part1c(const int* __restrict__ src, const int* __restrict__ dst,
                                                const unsigned* __restrict__ histD, const unsigned* __restrict__ histS,
                                                unsigned* __restrict__ pairD, unsigned* __restrict__ pairS, int E) {
  __shared__ unsigned pk[CHK];
  __shared__ unsigned char bk[CHK];
  __shared__ unsigned hist[256], cur[256], gbase[256], psc[256];
  int chunk = (E + gridDim.x - 1) / gridDim.x;
  int e0 = blockIdx.x * chunk, e1 = min(E, e0 + chunk);
  int n = e1 - e0;
  int t = threadIdx.x;
#pragma unroll
  for (int table = 0; table < 2; ++table) {
    const unsigned* gcur = (table ? histS : histD) + blockIdx.x * 256;
    unsigned* out = table ? pairS : pairD;
    hist[t] = 0;
    __syncthreads();
    for (int i = t; i < n; i += 256) {
      unsigned key = (unsigned)(table ? src[e0 + i] : dst[e0 + i]);
      atomicAdd(&hist[key >> 9], 1u);
    }
    __syncthreads();
    unsigned v = hist[t];
    psc[t] = v;
    __syncthreads();
    for (int off = 1; off < 256; off <<= 1) {
      unsigned x = (t >= off) ? psc[t - off] : 0;
      __syncthreads();
      psc[t] += x;
      __syncthreads();
    }
    unsigned excl = psc[t] - v;
    cur[t] = excl;
    gbase[t] = gcur[t] - excl;
    __syncthreads();
    for (int i = t; i < n; i += 256) {
      unsigned sv = (unsigned)src[e0 + i], dv = (unsigned)dst[e0 + i];
      unsigned key = table ? sv : dv;
      unsigned val = table ? (((sv & 511u) << 17) | dv) : (((dv & 511u) << 17) | sv);
      unsigned b = key >> 9;
      unsigned p = atomicAdd(&cur[b], 1u);
      pk[p] = val;
      bk[p] = (unsigned char)b;
    }
    __syncthreads();
    for (int i = t; i < n; i += 256)
      out[gbase[bk[i]] + i] = pk[i];
    __syncthreads();
  }
}

// ---- pass 2d: per dst-bucket — hist, scan, write offs/degI, place srcS ----
__global__ __launch_bounds__(256) void k_part2d(const unsigned* __restrict__ pairD, const int* __restrict__ bsD,
                                                int* __restrict__ offs, int* __restrict__ degI,
                                                int* __restrict__ srcS, int N) {
  __shared__ unsigned hist[512], excl[512], psc[256];
  int k = blockIdx.x, base = k << 9;
  int b0 = bsD[k], b1 = bsD[k + 1];
  hist[threadIdx.x] = 0; hist[threadIdx.x + 256] = 0;
  __syncthreads();
  for (int i = b0 + threadIdx.x; i < b1; i += 256)
    atomicAdd(&hist[pairD[i] >> 17], 1u);
  __syncthreads();
  unsigned s0 = hist[2 * threadIdx.x], s1 = hist[2 * threadIdx.x + 1];
  unsigned pr = s0 + s1;
  psc[threadIdx.x] = pr;
  __syncthreads();
  for (int off = 1; off < 256; off <<= 1) {
    unsigned x = (threadIdx.x >= off) ? psc[threadIdx.x - off] : 0;
    __syncthreads();
    psc[threadIdx.x] += x;
    __syncthreads();
  }
  unsigned pex = psc[threadIdx.x] - pr;
  excl[2 * threadIdx.x] = pex;
  excl[2 * threadIdx.x + 1] = pex + s0;
  __syncthreads();
  for (int j = threadIdx.x; j < 512; j += 256) {
    int node = base + j;
    if (node <= N) offs[node] = b0 + (int)excl[j];
    if (node < N) degI[node] = (int)hist[j];
  }
  __syncthreads();
  for (int i = b0 + threadIdx.x; i < b1; i += 256) {
    unsigned pkv = pairD[i];
    unsigned pos = atomicAdd(&excl[pkv >> 17], 1u);
    srcS[b0 + (int)pos] = (int)(pkv & 0x1FFFFu);
  }
}

// ---- norms for dst side + packed (poolw, gid) ----
__global__ __launch_bounds__(256) void k_norm(const int* __restrict__ degI, const int* __restrict__ gcnt,
                                              const int* __restrict__ gid,
                                              float* __restrict__ ndst, uint2* __restrict__ pwg, int N) {
  int i = blockIdx.x * blockDim.x + threadIdx.x;
  if (i >= N) return;
  float gi = (float)degI[i]; gi = gi > 0.f ? gi : 1.f;
  float nd = rsqrtf(gi);
  ndst[i] = nd;
  float c = (float)gcnt[gid[i]]; c = c > 1.f ? c : 1.f;
  float w = nd / c;
  union { float f; unsigned u; } v; v.f = w;
  pwg[i] = make_uint2(v.u, (unsigned)gid[i]);
}

// ---- k_pw (fused part2s): per src-bucket — out-degree hist -> nsrc,
//      and 128 KB LDS P-tile -> blocked bf16 P_blk[(k>>3)][g][k&7] ----
__global__ __launch_bounds__(1024, 1) void k_pw(const unsigned* __restrict__ pairS, const int* __restrict__ bsS,
                                                const uint2* __restrict__ pwg,
                                                unsigned short* __restrict__ P16,
                                                float* __restrict__ nsrc, int N) {
  __shared__ float tile[512 * 64];   // 128 KB
  __shared__ unsigned hist[512];     // 2 KB
  int k = blockIdx.x, base = k << 9;
  int b0 = bsS[k], b1 = bsS[k + 1];
  for (int i = threadIdx.x; i < 512 * 64; i += 1024) tile[i] = 0.f;
  if (threadIdx.x < 512) hist[threadIdx.x] = 0;
  __syncthreads();
  for (int i = b0 + threadIdx.x; i < b1; i += 1024) {
    unsigned pkv = pairS[i];
    unsigned dv = pkv & 0x1FFFFu;
    unsigned sloc = pkv >> 17;
    atomicAdd(&hist[sloc], 1u);
    uint2 u = pwg[dv];
    union { unsigned u; float f; } w; w.u = u.x;
    atomicAdd(&tile[sloc * 64 + u.y], w.f);
  }
  __syncthreads();
  if (threadIdx.x < 512) {
    int node = base + threadIdx.x;
    if (node < N) {
      float g = (float)hist[threadIdx.x]; g = g > 0.f ? g : 1.f;
      nsrc[node] = rsqrtf(g);
    }
  }
  // blocked bf16 write: rows >= N are zero (tile untouched) -> poolgemm needs no K guard
  for (int grp = threadIdx.x; grp < 4096; grp += 1024) {
    int qb = grp >> 6, g = grp & 63;
    unsigned w0 = (unsigned)f2bf(tile[(qb * 8 + 0) * 64 + g]) | ((unsigned)f2bf(tile[(qb * 8 + 1) * 64 + g]) << 16);
    unsigned w1 = (unsigned)f2bf(tile[(qb * 8 + 2) * 64 + g]) | ((unsigned)f2bf(tile[(qb * 8 + 3) * 64 + g]) << 16);
    unsigned w2 = (unsigned)f2bf(tile[(qb * 8 + 4) * 64 + g]) | ((unsigned)f2bf(tile[(qb * 8 + 5) * 64 + g]) << 16);
    unsigned w3 = (unsigned)f2bf(tile[(qb * 8 + 6) * 64 + g]) | ((unsigned)f2bf(tile[(qb * 8 + 7) * 64 + g]) << 16);
    uint4 o = make_uint4(w0, w1, w2, w3);
    *(uint4*)(P16 + ((size_t)(base >> 3) + qb) * 512 + g * 8) = o;
  }
}

// ---- wprep: Wt[n][k] = bf16(W1[k][n]) ----
__global__ __launch_bounds__(128) void k_wprep(const float* __restrict__ W, unsigned short* __restrict__ Wt) {
  int n = blockIdx.x, k = threadIdx.x;
  Wt[n * 128 + k] = f2bf(W[k * 128 + n]);
}

// ---- GEMM1 (MFMA): Z8 = fp8( (X @ W1) * nsrc[row] ), LDS-free ----
__global__ __launch_bounds__(256) void k_gemm1(const float* __restrict__ X, const unsigned short* __restrict__ Wt,
                                               const float* __restrict__ nsrc,
                                               unsigned char* __restrict__ Z8, int N) {
  int wave = threadIdx.x >> 6, lane = threadIdx.x & 63;
  int quad = lane >> 4, l16 = lane & 15;
  int row0 = blockIdx.x * 64 + wave * 16;
  int arow = row0 + l16; if (arow >= N) arow = N - 1;
  const float* xr = X + (size_t)arow * 128 + quad * 8;
  f32x4 acc[8];
#pragma unroll
  for (int i = 0; i < 8; ++i) acc[i] = (f32x4){0.f, 0.f, 0.f, 0.f};
#pragma unroll
  for (int kb = 0; kb < 128; kb += 32) {
    float4 x0 = *(const float4*)(xr + kb);
    float4 x1 = *(const float4*)(xr + kb + 4);
    bf16x8 a;
    a[0] = (short)f2bf(x0.x); a[1] = (short)f2bf(x0.y);
    a[2] = (short)f2bf(x0.z); a[3] = (short)f2bf(x0.w);
    a[4] = (short)f2bf(x1.x); a[5] = (short)f2bf(x1.y);
    a[6] = (short)f2bf(x1.z); a[7] = (short)f2bf(x1.w);
#pragma unroll
    for (int nt = 0; nt < 8; ++nt) {
      bf16x8 b = *(const bf16x8*)(Wt + (size_t)(nt * 16 + l16) * 128 + kb + quad * 8);
      acc[nt] = __builtin_amdgcn_mfma_f32_16x16x32_bf16(a, b, acc[nt], 0, 0, 0);
    }
  }
  int rbase = row0 + quad * 4;
#pragma unroll
  for (int r = 0; r < 4; ++r) {
    int row = rbase + r;
    if (row < N) {
      float s = nsrc[row];
#pragma unroll
      for (int nt = 0; nt < 8; ++nt)
        Z8[(size_t)row * 128 + nt * 16 + l16] = f2fp8(acc[nt][r] * s);
    }
  }
}

// ---- layer1 v3: quarter-wave owns a dst (4 dsts/wave), packed f32x2 acc ----
// Each 16-lane quarter processes its dst's full edge list: 1 edge = 16 lanes
// x 8 B (uint2). Accumulators stay in-lane -> NO cross-lane reduce, epilogue
// on all 64 lanes. 2-edge pipelined gather with predicated loads and
// unconditional accumulate (inactive slots add cvt(0) == 0).
#define ACCP(u) do {                                              \
    c0 += __builtin_amdgcn_cvt_pk_f32_fp8((u).x, false);          \
    c1 += __builtin_amdgcn_cvt_pk_f32_fp8((u).x, true);           \
    c2 += __builtin_amdgcn_cvt_pk_f32_fp8((u).y, false);          \
    c3 += __builtin_amdgcn_cvt_pk_f32_fp8((u).y, true);           \
  } while (0)

__global__ __launch_bounds__(256) void k_layer1(const unsigned char* __restrict__ Z8,
                                                const int* __restrict__ offs, const int* __restrict__ srcS,
                                                const float* __restrict__ b1,
                                                const float* __restrict__ nsrc, const float* __restrict__ ndst,
                                                unsigned short* __restrict__ Hb, int N) {
  int lane = threadIdx.x & 63;
  int q = lane >> 4, l16 = lane & 15;
  int d = blockIdx.x * 16 + (threadIdx.x >> 6) * 4 + q;
  bool live = d < N;
  int dc = live ? d : N - 1;
  int start = offs[dc];
  int end = live ? offs[dc + 1] : start;
  const int boff = l16 * 8;
  const unsigned char* zb = Z8 + boff;
  // hoist epilogue operands early (latency hidden under the gather loop)
  float4 bv0 = *(const float4*)(b1 + boff);
  float4 bv1 = *(const float4*)(b1 + boff + 4);
  float nd = ndst[dc], ns = nsrc[dc];
  f32x2 c0 = {0.f, 0.f}, c1 = {0.f, 0.f}, c2 = {0.f, 0.f}, c3 = {0.f, 0.f};
  int e = start;
  int rem = end - start;
  int s0 = (rem > 0) ? srcS[e] : 0;
  int s1 = (rem > 1) ? srcS[e + 1] : 0;
  while (__any(rem > 0)) {
    uint2 u0 = make_uint2(0u, 0u), u1 = make_uint2(0u, 0u);
    if (rem > 0) u0 = *(const uint2*)(zb + ((size_t)s0 << 7));
    if (rem > 1) u1 = *(const uint2*)(zb + ((size_t)s1 << 7));
    int rem2 = rem - 2;
    if (rem2 > 0) {            // prefetch next pair before consuming gathers
      s0 = srcS[e + 2];
      if (rem2 > 1) s1 = srcS[e + 3];
    }
    ACCP(u0);
    ACCP(u1);
    e += 2;
    rem = rem2;
  }
  if (live) {
    float h0 = fmaxf(fmaf(nd, c0[0], bv0.x), 0.f) * ns;
    float h1 = fmaxf(fmaf(nd, c0[1], bv0.y), 0.f) * ns;
    float h2 = fmaxf(fmaf(nd, c1[0], bv0.z), 0.f) * ns;
    float h3 = fmaxf(fmaf(nd, c1[1], bv0.w), 0.f) * ns;
    float h4 = fmaxf(fmaf(nd, c2[0], bv1.x), 0.f) * ns;
    float h5 = fmaxf(fmaf(nd, c2[1], bv1.y), 0.f) * ns;
    float h6 = fmaxf(fmaf(nd, c3[0], bv1.z), 0.f) * ns;
    float h7 = fmaxf(fmaf(nd, c3[1], bv1.w), 0.f) * ns;
    unsigned w0 = (unsigned)f2bf(h0) | ((unsigned)f2bf(h1) << 16);
    unsigned w1 = (unsigned)f2bf(h2) | ((unsigned)f2bf(h3) << 16);
    unsigned w2 = (unsigned)f2bf(h4) | ((unsigned)f2bf(h5) << 16);
    unsigned w3 = (unsigned)f2bf(h6) | ((unsigned)f2bf(h7) << 16);
    *(uint4*)(Hb + (size_t)d * 128 + boff) = make_uint4(w0, w1, w2, w3);
  }
}

// ---- k_poolgemm (MFMA): part[b] = P_blk^T · H  (split-K, bf16 inputs, f32 acc) ----
// wave w owns g-tile w; A-frag = one 16B load from P_blk; B-frag from swizzled LDS H.
__global__ __launch_bounds__(256) void k_poolgemm(const unsigned short* __restrict__ P16,
                                                  const unsigned short* __restrict__ Hb,
                                                  float* __restrict__ part, int N, int Kpad, int chunk) {
  __shared__ unsigned short Hl[KC * 128];   // 8 KB, 16-short groups XOR-swizzled by (row>>3)
  int t = threadIdx.x;
  int r0 = blockIdx.x * chunk;
  int r1 = min(Kpad, r0 + chunk);
  int wv = t >> 6, lane = t & 63, quad = lane >> 4, l16 = lane & 15;
  f32x4 acc[8];
#pragma unroll
  for (int i = 0; i < 8; ++i) acc[i] = (f32x4){0.f, 0.f, 0.f, 0.f};
  for (int rb = r0; rb < r1; rb += KC) {
    int r = t >> 3, c = (t & 7) * 16;
    int cs = c ^ ((r >> 3) * 16);        // swizzle 16-short group by row-octet
    int row = rb + r;
    if (row < N) {
      const uint4* srcp = (const uint4*)(Hb + (size_t)row * 128 + c);
      *(uint4*)(Hl + r * 128 + cs) = srcp[0];
      *(uint4*)(Hl + r * 128 + cs + 8) = srcp[1];
    } else {
      uint4 z = make_uint4(0, 0, 0, 0);
      *(uint4*)(Hl + r * 128 + cs) = z;
      *(uint4*)(Hl + r * 128 + cs + 8) = z;
    }
    __syncthreads();
    bf16x8 a = *(const bf16x8*)(P16 + ((size_t)(rb >> 3) + quad) * 512 + (wv * 16 + l16) * 8);
#pragma unroll
    for (int ft = 0; ft < 8; ++ft) {
      bf16x8 b;
#pragma unroll
      for (int j = 0; j < 8; ++j) {
        int rr = quad * 8 + j;
        b[j] = (short)Hl[rr * 128 + ((ft ^ (rr >> 3)) * 16) + l16];
      }
      acc[ft] = __builtin_amdgcn_mfma_f32_16x16x32_bf16(a, b, acc[ft], 0, 0, 0);
    }
    __syncthreads();
  }
  float* bp = part + (size_t)blockIdx.x * 64 * DD;
#pragma unroll
  for (int ft = 0; ft < 8; ++ft)
#pragma unroll
    for (int rg = 0; rg < 4; ++rg)
      bp[(wv * 16 + quad * 4 + rg) * DD + ft * 16 + l16] = acc[ft][rg];
}

// ---- fold split-K partials into pooled (zero-init) ----
__global__ __launch_bounds__(256) void k_fold(const float* __restrict__ part, float* __restrict__ pooled) {
  int tid = blockIdx.x * 256 + threadIdx.x;   // grid 256 -> 65536 threads, 8 groups
  int o = tid & 8191, grp = tid >> 13;
  float s = 0.f;
  for (int k = grp; k < GB; k += 8) s += part[(size_t)k * 8192 + o];
  unsafeAtomicAdd(&pooled[o], s);
}

// ---- out = pooled @ W2 + b2 ----
__global__ __launch_bounds__(128) void k_out(const float* __restrict__ pooled, const float* __restrict__ W2,
                                             const float* __restrict__ b2, float* __restrict__ out) {
  __shared__ float p[DD];
  int g = blockIdx.x, d = threadIdx.x;
  p[d] = pooled[g * DD + d];
  __syncthreads();
  float a = b2[d];
#pragma unroll 4
  for (int k = 0; k < DD; ++k) a = fmaf(p[k], W2[k * DD + d], a);
  out[g * DD + d] = a;
}

extern "C" void kernel_launch(void* const* d_in, const int* in_sizes, int n_in,
                              void* d_out, int out_size, void* d_ws, size_t ws_size,
                              hipStream_t stream) {
  const float* X  = (const float*)d_in[0];
  const float* W1 = (const float*)d_in[1];
  const float* b1 = (const float*)d_in[2];
  const float* W2 = (const float*)d_in[3];
  const float* b2 = (const float*)d_in[4];
  const int* src  = (const int*)d_in[5];
  const int* dst  = (const int*)d_in[6];
  const int* gid  = (const int*)d_in[7];
  int E = in_sizes[5];
  int N = in_sizes[7];
  int G = out_size / DD;   // 64
  int nb = (N >> 9) + 1;   // node buckets
  int Kpad = nb << 9;
  int chunk = ((Kpad + GB * KC - 1) / (GB * KC)) * KC;

  char* w = (char*)d_ws;
  size_t o = 0;
  auto carve = [&](size_t bytes) { char* p = w + o; o += (bytes + 255) & ~(size_t)255; return p; };
  // zero-init region
  int*   gcnt   = (int*)  carve((size_t)G * 4);
  float* pooled = (float*)carve((size_t)G * DD * 4);
  size_t zeroBytes = o;
  // rest (fully written before read)
  unsigned* histD = (unsigned*)carve((size_t)PB * 256 * 4);
  unsigned* histS = (unsigned*)carve((size_t)PB * 256 * 4);
  unsigned* tot   = (unsigned*)carve(512 * 4);
  int*   bsD    = (int*)  carve(257 * 4);
  int*   bsS    = (int*)  carve(257 * 4);
  unsigned* pairD = (unsigned*)carve((size_t)E * 4);  // } pairD+pairS (12.8 MB) aliased as part
  unsigned* pairS = (unsigned*)carve((size_t)E * 4);  // }   (GB*32KB = 12.58 MB fits)
  int*   srcS   = (int*)  carve((size_t)E * 4);
  int*   offs   = (int*)  carve((size_t)(N + 1) * 4);
  int*   degI   = (int*)  carve((size_t)N * 4);
  float* nsrc   = (float*)carve((size_t)N * 4);
  float* ndst   = (float*)carve((size_t)N * 4);
  uint2* pwg    = (uint2*)carve((size_t)N * 8);
  unsigned short* Wt = (unsigned short*)carve(128 * 128 * 2);
  unsigned char*  Z8 = (unsigned char*)carve((size_t)N * DD);       // fp8
  unsigned short* Hb = (unsigned short*)carve((size_t)N * DD * 2);
  unsigned short* P16 = (unsigned short*)carve((size_t)Kpad * 64 * 2);  // blocked bf16
  float* part   = (float*)pairD;   // pairD dead after part2d, pairS dead after k_pw

  hipMemsetAsync(d_ws, 0, zeroBytes, stream);

  k_part1a<<<PB, 256, 0, stream>>>(src, dst, gid, histD, histS, gcnt, E, N, G);
  k_pscanA<<<512, 256, 0, stream>>>(histD, histS, tot);
  k_pscanB<<<1, 256, 0, stream>>>(tot, bsD, bsS);
  k_pscanC<<<2 * PB, 256, 0, stream>>>(histD, histS, bsD, bsS);
  k_part1c<<<PB, 256, 0, stream>>>(src, dst, histD, histS, pairD, pairS, E);
  k_part2d<<<nb, 256, 0, stream>>>(pairD, bsD, offs, degI, srcS, N);
  k_norm<<<(N + 255) / 256, 256, 0, stream>>>(degI, gcnt, gid, ndst, pwg, N);
  k_pw<<<nb, 1024, 0, stream>>>(pairS, bsS, pwg, P16, nsrc, N);
  k_wprep<<<128, 128, 0, stream>>>(W1, Wt);
  k_gemm1<<<(N + 63) / 64, 256, 0, stream>>>(X, Wt, nsrc, Z8, N);
  k_layer1<<<(N + 15) / 16, 256, 0, stream>>>(Z8, offs, srcS, b1, nsrc, ndst, Hb, N);
  k_poolgemm<<<GB, 256, 0, stream>>>(P16, Hb, part, N, Kpad, chunk);
  k_fold<<<256, 256, 0, stream>>>(part, pooled);
  k_out<<<G, DD, 0, stream>>>(pooled, W2, b2, (float*)d_out);
}

// Round 3
// 291.834 us; speedup vs baseline: 1.0720x; 1.0234x over previous
//
#include <hip/hip_runtime.h>
#include <cstdint>

// GCN via radix partition (bucket = node>>9), packed u32 edge records.
// part1c v2: single pass over (src,dst), BOTH tables staged in LDS at once;
//            local hists come from raw counts saved by part1a.
// part2d: norm computation fused (degI never leaves LDS).
// poolgemm: split-K partials folded via device atomics (k_fold removed).
// layer1 v4: quarter-wave owns a dst, 4-deep pipelined gather.

#define DD 128
#define PB 512    // partition pass-1 blocks
#define GB 384    // poolgemm split-K blocks
#define KC 32     // poolgemm K-chunk
#define CHK 3200  // max edges per part1c block

typedef __attribute__((ext_vector_type(8))) short bf16x8;
typedef __attribute__((ext_vector_type(4))) float f32x4;
typedef __attribute__((ext_vector_type(2))) float f32x2;

__device__ __forceinline__ unsigned short f2bf(float f) {
  union { float f; unsigned u; } v; v.f = f;
  unsigned r = (v.u + 0x7fff + ((v.u >> 16) & 1)) >> 16;   // round-nearest-even
  return (unsigned short)r;
}
__device__ __forceinline__ unsigned char f2fp8(float f) {
  return (unsigned char)(__builtin_amdgcn_cvt_pk_fp8_f32(f, f, 0, false) & 0xff);
}

// ---- pass 1a: per-block 256-bin LDS histograms of dst>>9 and src>>9 + gcnt ----
// Writes cursor arrays (histD/histS, consumed by pscans) AND raw counts
// (rawD/rawS, consumed by part1c's local sort).
__global__ __launch_bounds__(256) void k_part1a(const int* __restrict__ src, const int* __restrict__ dst,
                                                const int* __restrict__ gid,
                                                unsigned* __restrict__ histD, unsigned* __restrict__ histS,
                                                unsigned* __restrict__ rawD, unsigned* __restrict__ rawS,
                                                int* __restrict__ gcnt, int E, int N, int G) {
  __shared__ unsigned hD[256], hS[256];
  __shared__ int h64[64];
  hD[threadIdx.x] = 0; hS[threadIdx.x] = 0;
  if (threadIdx.x < 64) h64[threadIdx.x] = 0;
  __syncthreads();
  int chunk = (E + gridDim.x - 1) / gridDim.x;
  int e0 = blockIdx.x * chunk, e1 = min(E, e0 + chunk);
  for (int e = e0 + threadIdx.x; e < e1; e += 256) {
    atomicAdd(&hD[(unsigned)dst[e] >> 9], 1u);
    atomicAdd(&hS[(unsigned)src[e] >> 9], 1u);
  }
  int stride = gridDim.x * 256;
  for (int i = blockIdx.x * 256 + threadIdx.x; i < N; i += stride)
    atomicAdd(&h64[gid[i]], 1);
  __syncthreads();
  unsigned vd = hD[threadIdx.x], vs = hS[threadIdx.x];
  histD[blockIdx.x * 256 + threadIdx.x] = vd;
  histS[blockIdx.x * 256 + threadIdx.x] = vs;
  rawD[blockIdx.x * 256 + threadIdx.x] = vd;
  rawS[blockIdx.x * 256 + threadIdx.x] = vs;
  if (threadIdx.x < (unsigned)G) {
    int v = h64[threadIdx.x];
    if (v) atomicAdd(&gcnt[threadIdx.x], v);
  }
}

// ---- pscanA: per (table,bucket) — scan the PB per-block counts ----
__global__ __launch_bounds__(256) void k_pscanA(unsigned* __restrict__ histD, unsigned* __restrict__ histS,
                                                unsigned* __restrict__ tot) {
  __shared__ unsigned excl[PB], psc[256];
  int table = blockIdx.x >> 8, b = blockIdx.x & 255;
  unsigned* hist = table ? histS : histD;
  int t = threadIdx.x;
  unsigned s0 = hist[(2 * t) * 256 + b];
  unsigned s1 = hist[(2 * t + 1) * 256 + b];
  unsigned pr = s0 + s1;
  psc[t] = pr;
  __syncthreads();
  for (int off = 1; off < 256; off <<= 1) {
    unsigned x = (t >= off) ? psc[t - off] : 0;
    __syncthreads();
    psc[t] += x;
    __syncthreads();
  }
  unsigned pex = psc[t] - pr;
  excl[2 * t] = pex;
  excl[2 * t + 1] = pex + s0;
  __syncthreads();
  hist[(2 * t) * 256 + b] = excl[2 * t];
  hist[(2 * t + 1) * 256 + b] = excl[2 * t + 1];
  if (t == 255) tot[table * 256 + b] = psc[255];
}

// ---- pscanB: one block — scan bucket totals for both tables ----
__global__ __launch_bounds__(256) void k_pscanB(const unsigned* __restrict__ tot,
                                                int* __restrict__ bsD, int* __restrict__ bsS) {
  __shared__ unsigned s[256];
  int t = threadIdx.x;
#pragma unroll
  for (int table = 0; table < 2; ++table) {
    int* bs = table ? bsS : bsD;
    unsigned v = tot[table * 256 + t];
    s[t] = v;
    __syncthreads();
    for (int off = 1; off < 256; off <<= 1) {
      unsigned x = (t >= off) ? s[t - off] : 0;
      __syncthreads();
      s[t] += x;
      __syncthreads();
    }
    bs[t] = (int)(s[t] - v);
    if (t == 255) bs[256] = (int)s[255];
    __syncthreads();
  }
}

// ---- pscanC: add bucket base into per-(block,bucket) cursors ----
__global__ __launch_bounds__(256) void k_pscanC(unsigned* __restrict__ histD, unsigned* __restrict__ histS,
                                                const int* __restrict__ bsD, const int* __restrict__ bsS) {
  int table = blockIdx.x >> 9, i = blockIdx.x & (PB - 1);
  unsigned* hist = table ? histS : histD;
  const int* bs = table ? bsS : bsD;
  hist[i * 256 + threadIdx.x] += (unsigned)bs[threadIdx.x];
}

// ---- pass 1c v2: ONE pass over (src,dst), both tables LDS-staged, then
//      ordered run write-out per table.
// pairD: (dst&511)<<17 | src ; pairS: (src&511)<<17 | dst   (N < 2^17)
__global__ __launch_bounds__(256) void k_part1c(const int* __restrict__ src, const int* __restrict__ dst,
                                                const unsigned* __restrict__ histD, const unsigned* __restrict__ histS,
                                                const unsigned* __restrict__ rawD, const unsigned* __restrict__ rawS,
                                                unsigned* __restrict__ pairD, unsigned* __restrict__ pairS, int E) {
  __shared__ unsigned pkD[CHK], pkS[CHK];
  __shared__ unsigned char bkD[CHK], bkS[CHK];
  __shared__ unsigned curD[256], curS[256], gbD[256], gbS[256], psc[256];
  int chunk = (E + gridDim.x - 1) / gridDim.x;
  int e0 = blockIdx.x * chunk, e1 = min(E, e0 + chunk);
  int n = e1 - e0;
  int t = threadIdx.x;
  // local exclusive scan of D counts (from raw array, no edge re-read)
  unsigned vD = rawD[blockIdx.x * 256 + t];
  psc[t] = vD;
  __syncthreads();
  for (int off = 1; off < 256; off <<= 1) {
    unsigned x = (t >= off) ? psc[t - off] : 0;
    __syncthreads();
    psc[t] += x;
    __syncthreads();
  }
  unsigned exD = psc[t] - vD;
  curD[t] = exD;
  gbD[t] = histD[blockIdx.x * 256 + t] - exD;
  __syncthreads();
  // local exclusive scan of S counts
  unsigned vS = rawS[blockIdx.x * 256 + t];
  psc[t] = vS;
  __syncthreads();
  for (int off = 1; off < 256; off <<= 1) {
    unsigned x = (t >= off) ? psc[t - off] : 0;
    __syncthreads();
    psc[t] += x;
    __syncthreads();
  }
  unsigned exS = psc[t] - vS;
  curS[t] = exS;
  gbS[t] = histS[blockIdx.x * 256 + t] - exS;
  __syncthreads();
  // single placement pass: both tables
  for (int i = t; i < n; i += 256) {
    unsigned sv = (unsigned)src[e0 + i], dv = (unsigned)dst[e0 + i];
    unsigned bD = dv >> 9, bS = sv >> 9;
    unsigned pD = atomicAdd(&curD[bD], 1u);
    pkD[pD] = ((dv & 511u) << 17) | sv;
    bkD[pD] = (unsigned char)bD;
    unsigned pS = atomicAdd(&curS[bS], 1u);
    pkS[pS] = ((sv & 511u) << 17) | dv;
    bkS[pS] = (unsigned char)bS;
  }
  __syncthreads();
  for (int i = t; i < n; i += 256)
    pairD[gbD[bkD[i]] + i] = pkD[i];
  for (int i = t; i < n; i += 256)
    pairS[gbS[bkS[i]] + i] = pkS[i];
}

// ---- pass 2d (+norm fused): per dst-bucket — hist, scan, offs, place srcS,
//      and ndst/pwg straight from the in-LDS degree counts ----
__global__ __launch_bounds__(256) void k_part2d(const unsigned* __restrict__ pairD, const int* __restrict__ bsD,
                                                const int* __restrict__ gcnt, const int* __restrict__ gid,
                                                int* __restrict__ offs, float* __restrict__ ndst,
                                                uint2* __restrict__ pwg,
                                                int* __restrict__ srcS, int N) {
  __shared__ unsigned hist[512], excl[512], psc[256];
  int k = blockIdx.x, base = k << 9;
  int b0 = bsD[k], b1 = bsD[k + 1];
  hist[threadIdx.x] = 0; hist[threadIdx.x + 256] = 0;
  __syncthreads();
  for (int i = b0 + threadIdx.x; i < b1; i += 256)
    atomicAdd(&hist[pairD[i] >> 17], 1u);
  __syncthreads();
  unsigned s0 = hist[2 * threadIdx.x], s1 = hist[2 * threadIdx.x + 1];
  unsigned pr = s0 + s1;
  psc[threadIdx.x] = pr;
  __syncthreads();
  for (int off = 1; off < 256; off <<= 1) {
    unsigned x = (threadIdx.x >= off) ? psc[threadIdx.x - off] : 0;
    __syncthreads();
    psc[threadIdx.x] += x;
    __syncthreads();
  }
  unsigned pex = psc[threadIdx.x] - pr;
  excl[2 * threadIdx.x] = pex;
  excl[2 * threadIdx.x + 1] = pex + s0;
  __syncthreads();
  for (int j = threadIdx.x; j < 512; j += 256) {
    int node = base + j;
    if (node <= N) offs[node] = b0 + (int)excl[j];
    if (node < N) {
      float gi = (float)hist[j]; gi = gi > 0.f ? gi : 1.f;
      float nd = rsqrtf(gi);
      ndst[node] = nd;
      float c = (float)gcnt[gid[node]]; c = c > 1.f ? c : 1.f;
      float w = nd / c;
      union { float f; unsigned u; } v; v.f = w;
      pwg[node] = make_uint2(v.u, (unsigned)gid[node]);
    }
  }
  __syncthreads();
  for (int i = b0 + threadIdx.x; i < b1; i += 256) {
    unsigned pkv = pairD[i];
    unsigned pos = atomicAdd(&excl[pkv >> 17], 1u);
    srcS[b0 + (int)pos] = (int)(pkv & 0x1FFFFu);
  }
}

// ---- k_pw (fused part2s): per src-bucket — out-degree hist -> nsrc,
//      and 128 KB LDS P-tile -> blocked bf16 P_blk[(k>>3)][g][k&7] ----
__global__ __launch_bounds__(1024, 1) void k_pw(const unsigned* __restrict__ pairS, const int* __restrict__ bsS,
                                                const uint2* __restrict__ pwg,
                                                unsigned short* __restrict__ P16,
                                                float* __restrict__ nsrc, int N) {
  __shared__ float tile[512 * 64];   // 128 KB
  __shared__ unsigned hist[512];     // 2 KB
  int k = blockIdx.x, base = k << 9;
  int b0 = bsS[k], b1 = bsS[k + 1];
  for (int i = threadIdx.x; i < 512 * 64; i += 1024) tile[i] = 0.f;
  if (threadIdx.x < 512) hist[threadIdx.x] = 0;
  __syncthreads();
  for (int i = b0 + threadIdx.x; i < b1; i += 1024) {
    unsigned pkv = pairS[i];
    unsigned dv = pkv & 0x1FFFFu;
    unsigned sloc = pkv >> 17;
    atomicAdd(&hist[sloc], 1u);
    uint2 u = pwg[dv];
    union { unsigned u; float f; } w; w.u = u.x;
    atomicAdd(&tile[sloc * 64 + u.y], w.f);
  }
  __syncthreads();
  if (threadIdx.x < 512) {
    int node = base + threadIdx.x;
    if (node < N) {
      float g = (float)hist[threadIdx.x]; g = g > 0.f ? g : 1.f;
      nsrc[node] = rsqrtf(g);
    }
  }
  // blocked bf16 write: rows >= N are zero (tile untouched) -> poolgemm needs no K guard
  for (int grp = threadIdx.x; grp < 4096; grp += 1024) {
    int qb = grp >> 6, g = grp & 63;
    unsigned w0 = (unsigned)f2bf(tile[(qb * 8 + 0) * 64 + g]) | ((unsigned)f2bf(tile[(qb * 8 + 1) * 64 + g]) << 16);
    unsigned w1 = (unsigned)f2bf(tile[(qb * 8 + 2) * 64 + g]) | ((unsigned)f2bf(tile[(qb * 8 + 3) * 64 + g]) << 16);
    unsigned w2 = (unsigned)f2bf(tile[(qb * 8 + 4) * 64 + g]) | ((unsigned)f2bf(tile[(qb * 8 + 5) * 64 + g]) << 16);
    unsigned w3 = (unsigned)f2bf(tile[(qb * 8 + 6) * 64 + g]) | ((unsigned)f2bf(tile[(qb * 8 + 7) * 64 + g]) << 16);
    uint4 o = make_uint4(w0, w1, w2, w3);
    *(uint4*)(P16 + ((size_t)(base >> 3) + qb) * 512 + g * 8) = o;
  }
}

// ---- wprep: Wt[n][k] = bf16(W1[k][n]) ----
__global__ __launch_bounds__(128) void k_wprep(const float* __restrict__ W, unsigned short* __restrict__ Wt) {
  int n = blockIdx.x, k = threadIdx.x;
  Wt[n * 128 + k] = f2bf(W[k * 128 + n]);
}

// ---- GEMM1 (MFMA): Z8 = fp8( (X @ W1) * nsrc[row] ), LDS-free ----
__global__ __launch_bounds__(256) void k_gemm1(const float* __restrict__ X, const unsigned short* __restrict__ Wt,
                                               const float* __restrict__ nsrc,
                                               unsigned char* __restrict__ Z8, int N) {
  int wave = threadIdx.x >> 6, lane = threadIdx.x & 63;
  int quad = lane >> 4, l16 = lane & 15;
  int row0 = blockIdx.x * 64 + wave * 16;
  int arow = row0 + l16; if (arow >= N) arow = N - 1;
  const float* xr = X + (size_t)arow * 128 + quad * 8;
  f32x4 acc[8];
#pragma unroll
  for (int i = 0; i < 8; ++i) acc[i] = (f32x4){0.f, 0.f, 0.f, 0.f};
#pragma unroll
  for (int kb = 0; kb < 128; kb += 32) {
    float4 x0 = *(const float4*)(xr + kb);
    float4 x1 = *(const float4*)(xr + kb + 4);
    bf16x8 a;
    a[0] = (short)f2bf(x0.x); a[1] = (short)f2bf(x0.y);
    a[2] = (short)f2bf(x0.z); a[3] = (short)f2bf(x0.w);
    a[4] = (short)f2bf(x1.x); a[5] = (short)f2bf(x1.y);
    a[6] = (short)f2bf(x1.z); a[7] = (short)f2bf(x1.w);
#pragma unroll
    for (int nt = 0; nt < 8; ++nt) {
      bf16x8 b = *(const bf16x8*)(Wt + (size_t)(nt * 16 + l16) * 128 + kb + quad * 8);
      acc[nt] = __builtin_amdgcn_mfma_f32_16x16x32_bf16(a, b, acc[nt], 0, 0, 0);
    }
  }
  int rbase = row0 + quad * 4;
#pragma unroll
  for (int r = 0; r < 4; ++r) {
    int row = rbase + r;
    if (row < N) {
      float s = nsrc[row];
#pragma unroll
      for (int nt = 0; nt < 8; ++nt)
        Z8[(size_t)row * 128 + nt * 16 + l16] = f2fp8(acc[nt][r] * s);
    }
  }
}

// ---- layer1 v4: quarter-wave owns a dst (4 dsts/wave), 4-deep pipeline ----
// Each 16-lane quarter processes its dst's full edge list: 1 edge = 16 lanes
// x 8 B (uint2). 4 gathers in flight; indices for the next 4 slots prefetched
// before the gathers are consumed. Accumulate is unconditional (inactive
// slots add cvt(0) == 0).
#define ACCP(u) do {                                              \
    c0 += __builtin_amdgcn_cvt_pk_f32_fp8((u).x, false);          \
    c1 += __builtin_amdgcn_cvt_pk_f32_fp8((u).x, true);           \
    c2 += __builtin_amdgcn_cvt_pk_f32_fp8((u).y, false);          \
    c3 += __builtin_amdgcn_cvt_pk_f32_fp8((u).y, true);           \
  } while (0)

__global__ __launch_bounds__(256) void k_layer1(const unsigned char* __restrict__ Z8,
                                                const int* __restrict__ offs, const int* __restrict__ srcS,
                                                const float* __restrict__ b1,
                                                const float* __restrict__ nsrc, const float* __restrict__ ndst,
                                                unsigned short* __restrict__ Hb, int N) {
  int lane = threadIdx.x & 63;
  int q = lane >> 4, l16 = lane & 15;
  int d = blockIdx.x * 16 + (threadIdx.x >> 6) * 4 + q;
  bool live = d < N;
  int dc = live ? d : N - 1;
  int start = offs[dc];
  int end = live ? offs[dc + 1] : start;
  const int boff = l16 * 8;
  const unsigned char* zb = Z8 + boff;
  // hoist epilogue operands early (latency hidden under the gather loop)
  float4 bv0 = *(const float4*)(b1 + boff);
  float4 bv1 = *(const float4*)(b1 + boff + 4);
  float nd = ndst[dc], ns = nsrc[dc];
  f32x2 c0 = {0.f, 0.f}, c1 = {0.f, 0.f}, c2 = {0.f, 0.f}, c3 = {0.f, 0.f};
  int e = start;
  int rem = end - start;
  int s0 = 0, s1 = 0, s2 = 0, s3 = 0;
  if (rem > 0) s0 = srcS[e];
  if (rem > 1) s1 = srcS[e + 1];
  if (rem > 2) s2 = srcS[e + 2];
  if (rem > 3) s3 = srcS[e + 3];
  while (__any(rem > 0)) {
    uint2 u0 = make_uint2(0u, 0u), u1 = make_uint2(0u, 0u);
    uint2 u2 = make_uint2(0u, 0u), u3 = make_uint2(0u, 0u);
    if (rem > 0) u0 = *(const uint2*)(zb + ((size_t)s0 << 7));
    if (rem > 1) u1 = *(const uint2*)(zb + ((size_t)s1 << 7));
    if (rem > 2) u2 = *(const uint2*)(zb + ((size_t)s2 << 7));
    if (rem > 3) u3 = *(const uint2*)(zb + ((size_t)s3 << 7));
    if (rem > 4) s0 = srcS[e + 4];      // prefetch next 4 before consuming
    if (rem > 5) s1 = srcS[e + 5];
    if (rem > 6) s2 = srcS[e + 6];
    if (rem > 7) s3 = srcS[e + 7];
    ACCP(u0);
    ACCP(u1);
    ACCP(u2);
    ACCP(u3);
    e += 4;
    rem -= 4;
  }
  if (live) {
    float h0 = fmaxf(fmaf(nd, c0[0], bv0.x), 0.f) * ns;
    float h1 = fmaxf(fmaf(nd, c0[1], bv0.y), 0.f) * ns;
    float h2 = fmaxf(fmaf(nd, c1[0], bv0.z), 0.f) * ns;
    float h3 = fmaxf(fmaf(nd, c1[1], bv0.w), 0.f) * ns;
    float h4 = fmaxf(fmaf(nd, c2[0], bv1.x), 0.f) * ns;
    float h5 = fmaxf(fmaf(nd, c2[1], bv1.y), 0.f) * ns;
    float h6 = fmaxf(fmaf(nd, c3[0], bv1.z), 0.f) * ns;
    float h7 = fmaxf(fmaf(nd, c3[1], bv1.w), 0.f) * ns;
    unsigned w0 = (unsigned)f2bf(h0) | ((unsigned)f2bf(h1) << 16);
    unsigned w1 = (unsigned)f2bf(h2) | ((unsigned)f2bf(h3) << 16);
    unsigned w2 = (unsigned)f2bf(h4) | ((unsigned)f2bf(h5) << 16);
    unsigned w3 = (unsigned)f2bf(h6) | ((unsigned)f2bf(h7) << 16);
    *(uint4*)(Hb + (size_t)d * 128 + boff) = make_uint4(w0, w1, w2, w3);
  }
}

// ---- k_poolgemm (MFMA): pooled += P_blk^T · H  (split-K, bf16, f32 acc) ----
// Epilogue folds partials directly via device-scope f32 atomics (k_fold gone).
__global__ __launch_bounds__(256) void k_poolgemm(const unsigned short* __restrict__ P16,
                                                  const unsigned short* __restrict__ Hb,
                                                  float* __restrict__ pooled, int N, int Kpad, int chunk) {
  __shared__ unsigned short Hl[KC * 128];   // 8 KB, 16-short groups XOR-swizzled by (row>>3)
  int t = threadIdx.x;
  int r0 = blockIdx.x * chunk;
  int r1 = min(Kpad, r0 + chunk);
  int wv = t >> 6, lane = t & 63, quad = lane >> 4, l16 = lane & 15;
  f32x4 acc[8];
#pragma unroll
  for (int i = 0; i < 8; ++i) acc[i] = (f32x4){0.f, 0.f, 0.f, 0.f};
  for (int rb = r0; rb < r1; rb += KC) {
    int r = t >> 3, c = (t & 7) * 16;
    int cs = c ^ ((r >> 3) * 16);        // swizzle 16-short group by row-octet
    int row = rb + r;
    if (row < N) {
      const uint4* srcp = (const uint4*)(Hb + (size_t)row * 128 + c);
      *(uint4*)(Hl + r * 128 + cs) = srcp[0];
      *(uint4*)(Hl + r * 128 + cs + 8) = srcp[1];
    } else {
      uint4 z = make_uint4(0, 0, 0, 0);
      *(uint4*)(Hl + r * 128 + cs) = z;
      *(uint4*)(Hl + r * 128 + cs + 8) = z;
    }
    __syncthreads();
    bf16x8 a = *(const bf16x8*)(P16 + ((size_t)(rb >> 3) + quad) * 512 + (wv * 16 + l16) * 8);
#pragma unroll
    for (int ft = 0; ft < 8; ++ft) {
      bf16x8 b;
#pragma unroll
      for (int j = 0; j < 8; ++j) {
        int rr = quad * 8 + j;
        b[j] = (short)Hl[rr * 128 + ((ft ^ (rr >> 3)) * 16) + l16];
      }
      acc[ft] = __builtin_amdgcn_mfma_f32_16x16x32_bf16(a, b, acc[ft], 0, 0, 0);
    }
    __syncthreads();
  }
#pragma unroll
  for (int ft = 0; ft < 8; ++ft)
#pragma unroll
    for (int rg = 0; rg < 4; ++rg)
      unsafeAtomicAdd(&pooled[(wv * 16 + quad * 4 + rg) * DD + ft * 16 + l16], acc[ft][rg]);
}

// ---- out = pooled @ W2 + b2 ----
__global__ __launch_bounds__(128) void k_out(const float* __restrict__ pooled, const float* __restrict__ W2,
                                             const float* __restrict__ b2, float* __restrict__ out) {
  __shared__ float p[DD];
  int g = blockIdx.x, d = threadIdx.x;
  p[d] = pooled[g * DD + d];
  __syncthreads();
  float a = b2[d];
#pragma unroll 4
  for (int k = 0; k < DD; ++k) a = fmaf(p[k], W2[k * DD + d], a);
  out[g * DD + d] = a;
}

extern "C" void kernel_launch(void* const* d_in, const int* in_sizes, int n_in,
                              void* d_out, int out_size, void* d_ws, size_t ws_size,
                              hipStream_t stream) {
  const float* X  = (const float*)d_in[0];
  const float* W1 = (const float*)d_in[1];
  const float* b1 = (const float*)d_in[2];
  const float* W2 = (const float*)d_in[3];
  const float* b2 = (const float*)d_in[4];
  const int* src  = (const int*)d_in[5];
  const int* dst  = (const int*)d_in[6];
  const int* gid  = (const int*)d_in[7];
  int E = in_sizes[5];
  int N = in_sizes[7];
  int G = out_size / DD;   // 64
  int nb = (N >> 9) + 1;   // node buckets
  int Kpad = nb << 9;
  int chunk = ((Kpad + GB * KC - 1) / (GB * KC)) * KC;

  char* w = (char*)d_ws;
  size_t o = 0;
  auto carve = [&](size_t bytes) { char* p = w + o; o += (bytes + 255) & ~(size_t)255; return p; };
  // zero-init region
  int*   gcnt   = (int*)  carve((size_t)G * 4);
  float* pooled = (float*)carve((size_t)G * DD * 4);
  size_t zeroBytes = o;
  // rest (fully written before read)
  unsigned* histD = (unsigned*)carve((size_t)PB * 256 * 4);
  unsigned* histS = (unsigned*)carve((size_t)PB * 256 * 4);
  unsigned* rawD  = (unsigned*)carve((size_t)PB * 256 * 4);
  unsigned* rawS  = (unsigned*)carve((size_t)PB * 256 * 4);
  unsigned* tot   = (unsigned*)carve(512 * 4);
  int*   bsD    = (int*)  carve(257 * 4);
  int*   bsS    = (int*)  carve(257 * 4);
  unsigned* pairD = (unsigned*)carve((size_t)E * 4);
  unsigned* pairS = (unsigned*)carve((size_t)E * 4);
  int*   srcS   = (int*)  carve((size_t)E * 4);
  int*   offs   = (int*)  carve((size_t)(N + 1) * 4);
  float* nsrc   = (float*)carve((size_t)N * 4);
  float* ndst   = (float*)carve((size_t)N * 4);
  uint2* pwg    = (uint2*)carve((size_t)N * 8);
  unsigned short* Wt = (unsigned short*)carve(128 * 128 * 2);
  unsigned char*  Z8 = (unsigned char*)carve((size_t)N * DD);       // fp8
  unsigned short* Hb = (unsigned short*)carve((size_t)N * DD * 2);
  unsigned short* P16 = (unsigned short*)carve((size_t)Kpad * 64 * 2);  // blocked bf16

  hipMemsetAsync(d_ws, 0, zeroBytes, stream);

  k_part1a<<<PB, 256, 0, stream>>>(src, dst, gid, histD, histS, rawD, rawS, gcnt, E, N, G);
  k_pscanA<<<512, 256, 0, stream>>>(histD, histS, tot);
  k_pscanB<<<1, 256, 0, stream>>>(tot, bsD, bsS);
  k_pscanC<<<2 * PB, 256, 0, stream>>>(histD, histS, bsD, bsS);
  k_part1c<<<PB, 256, 0, stream>>>(src, dst, histD, histS, rawD, rawS, pairD, pairS, E);
  k_part2d<<<nb, 256, 0, stream>>>(pairD, bsD, gcnt, gid, offs, ndst, pwg, srcS, N);
  k_pw<<<nb, 1024, 0, stream>>>(pairS, bsS, pwg, P16, nsrc, N);
  k_wprep<<<128, 128, 0, stream>>>(W1, Wt);
  k_gemm1<<<(N + 63) / 64, 256, 0, stream>>>(X, Wt, nsrc, Z8, N);
  k_layer1<<<(N + 15) / 16, 256, 0, stream>>>(Z8, offs, srcS, b1, nsrc, ndst, Hb, N);
  k_poolgemm<<<GB, 256, 0, stream>>>(P16, Hb, pooled, N, Kpad, chunk);
  k_out<<<G, DD, 0, stream>>>(pooled, W2, b2, (float*)d_out);
}